// Round 7
// baseline (89.085 us; speedup 1.0000x reference)
//
#include <hip/hip_runtime.h>
#include <hip/hip_bf16.h>
#include <math.h>

#define B_  4096u
#define N_  8192
#define D_  128
#define M_  8190u          // negatives per logits row = 2B-2
#define SB_ 25159680u      // S_B = B*(2B-2) - B*(B-1)/2
#define NT2_ 1056          // upper-tri 128x256 tiles

#define AS1 __attribute__((address_space(1)))
#define AS3 __attribute__((address_space(3)))

typedef __attribute__((ext_vector_type(8))) short bf16x8;
typedef __attribute__((ext_vector_type(4))) float f32x4;
typedef __attribute__((ext_vector_type(4))) short short4v;

static __device__ __forceinline__ short f2b(float x) {
  __hip_bfloat16 h = __float2bfloat16(x);
  union { __hip_bfloat16 h; short s; } u; u.h = h; return u.s;
}
// cumulative flat-count of strict-upper (minus positives) elements before row i
static __device__ __forceinline__ unsigned rowS(unsigned i) {
  if (i <= B_) return i * (2u * B_ - 2u) - (i * (i - 1u)) / 2u;
  unsigned d = i - B_;
  return SB_ + d * (B_ - 1u) - (d * (d - 1u)) / 2u;
}
// cumulative tile count before row-panel m (128-row panels, 256-col tiles)
static __device__ __forceinline__ int tile0(int m) {
  return 32 * m - (m * m - 2 * m + (m & 1)) / 4;
}
// 16-lane (DPP row) rotation reduce: every lane gets the sum of its 16-group
template <int CTRL>
static __device__ __forceinline__ float dpp_add(float x) {
  union { float f; int i; } u, r;
  u.f = x;
  r.i = __builtin_amdgcn_mov_dpp(u.i, CTRL, 0xF, 0xF, 0);
  return x + r.f;
}
static __device__ __forceinline__ float rsum16(float x) {
  x = dpp_add<0x121>(x);   // row_ror:1
  x = dpp_add<0x122>(x);   // row_ror:2
  x = dpp_add<0x124>(x);   // row_ror:4
  x = dpp_add<0x128>(x);   // row_ror:8
  return x;
}

// ---------------------------------------------------------------------------
// Kernel A: normalize rows of reps=[zjs;zis] -> bf16 nb[row][k].
// Block 0 zeroes E buckets + panel counters + done counter (replay-safe).
// ---------------------------------------------------------------------------
__global__ __launch_bounds__(256) void nt_norm(
    const float* __restrict__ zis, const float* __restrict__ zjs,
    short* __restrict__ nb, unsigned* __restrict__ zbase) {
  const int t   = threadIdx.x;
  const int row = blockIdx.x * 8 + (t >> 5);
  const int c   = t & 31;
  const float* src = (row < (int)B_) ? (zjs + (size_t)row * D_)
                                     : (zis + (size_t)(row - (int)B_) * D_);
  float4 v = *(const float4*)(src + c * 4);
  float s = v.x * v.x + v.y * v.y + v.z * v.z + v.w * v.w;
  #pragma unroll
  for (int m = 16; m >= 1; m >>= 1) s += __shfl_xor(s, m, 32);
  float rn = 1.0f / fmaxf(sqrtf(s), 1e-8f);
  short4v o;
  o[0] = f2b(v.x * rn); o[1] = f2b(v.y * rn);
  o[2] = f2b(v.z * rn); o[3] = f2b(v.w * rn);
  *(short4v*)(nb + (size_t)row * D_ + c * 4) = o;

  if (blockIdx.x == 0) {
    // E (4112 f32) + pcnt (64 u32) + dcnt (1 u32), contiguous: 4177 words
    for (int r = t; r < 4177; r += 256) zbase[r] = 0u;
  }
}

// ---------------------------------------------------------------------------
// Kernel B: MEGA. 128x256-tile upper-tri Gram (bf16 MFMA, 8 waves 2x4),
// 3-buffer 2-ahead pipelined staging (counted vmcnt), inline bucket
// thresholds, DPP rotation reduce, partial store; then panel-chained
// reduction (last tile of panel) and final loss (64th panel finisher).
// ---------------------------------------------------------------------------
__global__ __launch_bounds__(512, 4) void nt_mega(
    const short* __restrict__ nb, float* __restrict__ posl,
    float2* __restrict__ part, float* __restrict__ E,
    unsigned* __restrict__ pcnt, unsigned* __restrict__ dcnt,
    float* __restrict__ out) {
  // XCD-chunked bijective swizzle: 1056 = 8 * 132
  const int tb = ((int)blockIdx.x & 7) * 132 + ((int)blockIdx.x >> 3);
  int bi2 = (int)(2.0f * (32.0f - sqrtf(fmaxf(0.f, 1024.0f - (float)tb))));
  if (bi2 > 63) bi2 = 63;
  while (bi2 > 0 && tb < tile0(bi2)) --bi2;
  while (tb >= tile0(bi2 + 1)) ++bi2;
  const int jlo = bi2 >> 1;
  const int bj2 = jlo + (tb - tile0(bi2));
  const int base = tile0(bi2);
  const int cnt  = 32 - jlo;                 // tiles in this panel

  __shared__ short As[3][128 * 32];          // 3 x 8KB
  __shared__ short Bs[3][256 * 32];          // 3 x 16KB
  __shared__ float2 red2[4][128];            // 4KB        total 76KB
  __shared__ unsigned srole;

  const int t    = threadIdx.x;
  const int lane = t & 63, wave = t >> 6;
  const int li   = lane & 15, hi = lane >> 4;
  const int wr   = wave >> 2, wc = wave & 3; // 2x4 wave grid
  const int i0   = bi2 * 128, j0 = bj2 * 256;

  const short* gA = nb + (size_t)i0 * D_;
  const short* gB = nb + (size_t)j0 * D_;

#define STAGE(ph, buf) do {                                                   \
    { int e_ = t; int r_ = e_ >> 2, sl_ = e_ & 3, sg_ = sl_ ^ ((r_ >> 1) & 3);\
      __builtin_amdgcn_global_load_lds(                                       \
          (const AS1 void*)(gA + (size_t)r_ * D_ + (ph) * 32 + sg_ * 8),      \
          (AS3 void*)(&As[buf][e_ * 8]), 16, 0, 0); }                         \
    _Pragma("unroll")                                                         \
    for (int it_ = 0; it_ < 2; ++it_) {                                       \
      int e_ = it_ * 512 + t;                                                 \
      int r_ = e_ >> 2, sl_ = e_ & 3, sg_ = sl_ ^ ((r_ >> 1) & 3);            \
      __builtin_amdgcn_global_load_lds(                                       \
          (const AS1 void*)(gB + (size_t)r_ * D_ + (ph) * 32 + sg_ * 8),      \
          (AS3 void*)(&Bs[buf][e_ * 8]), 16, 0, 0); }                         \
  } while (0)

  STAGE(0, 0);
  STAGE(1, 1);

  f32x4 acc[4][4];
  #pragma unroll
  for (int m = 0; m < 4; ++m)
    #pragma unroll
    for (int n = 0; n < 4; ++n) acc[m][n] = (f32x4){0.f, 0.f, 0.f, 0.f};

  const int sw = hi ^ ((li >> 1) & 3);       // swizzled 16B slot for ds_read

  #pragma unroll
  for (int ph = 0; ph < 4; ++ph) {
    if (ph < 2) STAGE(ph + 2, (ph + 2) % 3);
    if (ph < 2)       asm volatile("s_waitcnt vmcnt(6)" ::: "memory");
    else if (ph == 2) asm volatile("s_waitcnt vmcnt(3)" ::: "memory");
    else              asm volatile("s_waitcnt vmcnt(0)" ::: "memory");
    __builtin_amdgcn_s_barrier();
    __builtin_amdgcn_sched_barrier(0);

    const int cb = ph % 3;
    bf16x8 af[4], bfr[4];
    #pragma unroll
    for (int m = 0; m < 4; ++m)
      af[m] = *(const bf16x8*)(&As[cb][(wr * 64 + m * 16 + li) * 32 + sw * 8]);
    #pragma unroll
    for (int n = 0; n < 4; ++n)
      bfr[n] = *(const bf16x8*)(&Bs[cb][(wc * 64 + n * 16 + li) * 32 + sw * 8]);
    #pragma unroll
    for (int m = 0; m < 4; ++m)
      #pragma unroll
      for (int n = 0; n < 4; ++n)
        acc[m][n] = __builtin_amdgcn_mfma_f32_16x16x32_bf16(
            af[m], bfr[n], acc[m][n], 0, 0, 0);
    if (ph < 2) __builtin_amdgcn_s_barrier();  // buf (ph%3) overwritten next phase
  }
#undef STAGE

  // ---- epilogue: inline thresholds, bucket sums, DPP reduce ----
  const bool isdiag = (bj2 == jlo);
  const bool ispost = (bj2 == jlo + 16);
  const unsigned jw0 = (unsigned)(j0 + wc * 64);

  #pragma unroll
  for (int m = 0; m < 4; ++m) {
    #pragma unroll
    for (int rg = 0; rg < 4; ++rg) {
      const unsigned i = (unsigned)(i0 + wr * 64 + m * 16 + hi * 4 + rg);
      const unsigned S = rowS(i);
      unsigned T = (S / M_ + 1u) * M_ - S + i + 1u;
      T += ((i < B_) && (T > i + B_)) ? 1u : 0u;
      float s0 = 0.f, s1 = 0.f;
      if (isdiag | ispost) {
        #pragma unroll
        for (int n = 0; n < 4; ++n) {
          const unsigned j = jw0 + n * 16 + (unsigned)li;
          const bool ip = ispost && (j == i + B_);
          if (ip)
            __hip_atomic_store(&posl[i], 2.0f * acc[m][n][rg],
                               __ATOMIC_RELAXED, __HIP_MEMORY_SCOPE_AGENT);
          if ((j > i) && !ip) {
            float e = __expf(2.0f * acc[m][n][rg]);
            if (j < T) s0 += e; else s1 += e;
          }
        }
      } else if ((T > jw0) && (T < jw0 + 64u)) {   // straddle (rare)
        #pragma unroll
        for (int n = 0; n < 4; ++n) {
          const unsigned j = jw0 + n * 16 + (unsigned)li;
          float e = __expf(2.0f * acc[m][n][rg]);
          if (j < T) s0 += e; else s1 += e;
        }
      } else {                                      // uniform bucket
        float s = 0.f;
        #pragma unroll
        for (int n = 0; n < 4; ++n) s += __expf(2.0f * acc[m][n][rg]);
        if (T > jw0) s0 = s; else s1 = s;
      }
      s0 = rsum16(s0);
      s1 = rsum16(s1);
      if (li == 0)
        red2[wc][wr * 64 + m * 16 + hi * 4 + rg] = make_float2(s0, s1);
    }
  }
  __syncthreads();

  if (t < 128) {
    float2 s = make_float2(0.f, 0.f);
    #pragma unroll
    for (int w = 0; w < 4; ++w) {
      float2 v = red2[w][t];
      s.x += v.x; s.y += v.y;
    }
    union { float2 f; unsigned long long u; } cv; cv.f = s;
    __hip_atomic_store((unsigned long long*)(part + (size_t)tb * 128 + t),
                       cv.u, __ATOMIC_RELAXED, __HIP_MEMORY_SCOPE_AGENT);
  }
  __syncthreads();

  // ---- panel completion chain ----
  if (t == 0) {
    __threadfence();
    unsigned old = atomicAdd(&pcnt[bi2], 1u);
    srole = (old == (unsigned)(cnt - 1)) ? 1u : 0u;
  }
  __syncthreads();
  if (!srole) return;

  // this block is the LAST finisher of panel bi2: reduce the panel
  __threadfence();
  {
    const int row = t & 127, q = t >> 7;
    float2 ps = make_float2(0.f, 0.f);
    for (int c = q; c < cnt; c += 4) {
      unsigned long long raw = __hip_atomic_load(
          (const unsigned long long*)(part + (size_t)(base + c) * 128 + row),
          __ATOMIC_RELAXED, __HIP_MEMORY_SCOPE_AGENT);
      union { unsigned long long u; float2 f; } cv; cv.u = raw;
      ps.x += cv.f.x; ps.y += cv.f.y;
    }
    red2[q][row] = ps;
  }
  __syncthreads();
  if (t < 128) {
    float sx = 0.f, sy = 0.f;
    #pragma unroll
    for (int w = 0; w < 4; ++w) {
      float2 v = red2[w][t];
      sx += v.x; sy += v.y;
    }
    const unsigned i   = (unsigned)(i0 + t);
    const unsigned rlo = rowS(i) / M_;
    atomicAdd(&E[rlo],      sx);
    atomicAdd(&E[rlo + 1u], sy);
  }
  __threadfence();
  __syncthreads();
  if (t == 0) {
    unsigned od = atomicAdd(dcnt, 1u);
    srole = (od == 63u) ? 2u : 0u;
  }
  __syncthreads();
  if (srole != 2u) return;

  // ---- 64th panel finisher: the loss ----
  __threadfence();
  double* dred = (double*)&red2[0][0];       // 512 doubles = 4KB
  double acc2 = 0.0;
  for (int r = t; r < (int)B_; r += 512) {
    float ev = atomicAdd(&E[r], 0.0f);       // coherent read
    float pl = __hip_atomic_load(&posl[r], __ATOMIC_RELAXED,
                                 __HIP_MEMORY_SCOPE_AGENT);
    acc2 += (double)(logf(__expf(pl) + ev) - pl);
  }
  dred[t] = acc2;
  __syncthreads();
  for (int m = 256; m > 0; m >>= 1) {
    if (t < m) dred[t] += dred[t + m];
    __syncthreads();
  }
  if (t == 0) out[0] = (float)(dred[0] / (double)B_);
}

// ---------------------------------------------------------------------------
extern "C" void kernel_launch(void* const* d_in, const int* in_sizes, int n_in,
                              void* d_out, int out_size, void* d_ws, size_t ws_size,
                              hipStream_t stream) {
  const float* zis = (const float*)d_in[0];
  const float* zjs = (const float*)d_in[1];
  float* out = (float*)d_out;

  char* ws = (char*)d_ws;
  short*    nb   = (short*)ws;                         // 2 MB
  float*    posl = (float*)(ws + 2097152);             // 16 KB
  float2*   part = (float2*)(ws + 2113536);            // 1056*128*8 = 1.08 MB
  float*    E    = (float*)(ws + 3194880);             // 4112 f32
  unsigned* pcnt = (unsigned*)(ws + 3211328);          // 64 u32
  unsigned* dcnt = (unsigned*)(ws + 3211584);          // 1 u32
  unsigned* zb   = (unsigned*)E;                       // E+pcnt+dcnt contiguous

  nt_norm<<<dim3(N_ / 8), 256, 0, stream>>>(zis, zjs, nb, zb);
  nt_mega<<<dim3(NT2_),   512, 0, stream>>>(nb, posl, part, E, pcnt, dcnt, out);
}

// Round 8
// 55.021 us; speedup vs baseline: 1.6191x; 1.6191x over previous
//
#include <hip/hip_runtime.h>
#include <hip/hip_bf16.h>
#include <math.h>

#define B_  4096u
#define N_  8192
#define D_  128
#define M_  8190u          // negatives per logits row = 2B-2
#define SB_ 25159680u      // S_B = B*(2B-2) - B*(B-1)/2
#define NT2_ 1056          // upper-tri 128x256 tiles

#define AS1 __attribute__((address_space(1)))
#define AS3 __attribute__((address_space(3)))

typedef __attribute__((ext_vector_type(8))) short bf16x8;
typedef __attribute__((ext_vector_type(4))) float f32x4;
typedef __attribute__((ext_vector_type(4))) short short4v;

static __device__ __forceinline__ short f2b(float x) {
  __hip_bfloat16 h = __float2bfloat16(x);
  union { __hip_bfloat16 h; short s; } u; u.h = h; return u.s;
}
// cumulative flat-count of strict-upper (minus positives) elements before row i
static __device__ __forceinline__ unsigned rowS(unsigned i) {
  if (i <= B_) return i * (2u * B_ - 2u) - (i * (i - 1u)) / 2u;
  unsigned d = i - B_;
  return SB_ + d * (B_ - 1u) - (d * (d - 1u)) / 2u;
}
// cumulative tile count before row-panel m (128-row panels, 256-col tiles)
static __device__ __forceinline__ int tile0(int m) {
  return 32 * m - (m * m - 2 * m + (m & 1)) / 4;
}
// 16-lane DPP row_ror rotation reduce (validated R7): every lane of each
// 16-group ends with the group sum. VALU-rate, no LDS pipe.
template <int CTRL>
static __device__ __forceinline__ float dpp_add(float x) {
  union { float f; int i; } u, r;
  u.f = x;
  r.i = __builtin_amdgcn_mov_dpp(u.i, CTRL, 0xF, 0xF, 0);
  return x + r.f;
}
static __device__ __forceinline__ float rsum16(float x) {
  x = dpp_add<0x121>(x);   // row_ror:1
  x = dpp_add<0x122>(x);   // row_ror:2
  x = dpp_add<0x124>(x);   // row_ror:4
  x = dpp_add<0x128>(x);   // row_ror:8
  return x;
}

// ---------------------------------------------------------------------------
// Kernel A: normalize rows of reps=[zjs;zis] -> bf16 nb[row][k]; build Trow;
// block 0 zeroes E buckets + completion counter (replay-safe).
// ---------------------------------------------------------------------------
__global__ __launch_bounds__(256) void nt_norm(
    const float* __restrict__ zis, const float* __restrict__ zjs,
    short* __restrict__ nb, unsigned* __restrict__ Trow,
    unsigned* __restrict__ zbase) {
  const int t   = threadIdx.x;
  const int row = blockIdx.x * 8 + (t >> 5);
  const int c   = t & 31;
  const float* src = (row < (int)B_) ? (zjs + (size_t)row * D_)
                                     : (zis + (size_t)(row - (int)B_) * D_);
  float4 v = *(const float4*)(src + c * 4);
  float s = v.x * v.x + v.y * v.y + v.z * v.z + v.w * v.w;
  #pragma unroll
  for (int m = 16; m >= 1; m >>= 1) s += __shfl_xor(s, m, 32);
  float rn = 1.0f / fmaxf(sqrtf(s), 1e-8f);
  short4v o;
  o[0] = f2b(v.x * rn); o[1] = f2b(v.y * rn);
  o[2] = f2b(v.z * rn); o[3] = f2b(v.w * rn);
  *(short4v*)(nb + (size_t)row * D_ + c * 4) = o;

  if (t < 8) {
    unsigned i   = (unsigned)(blockIdx.x * 8 + t);
    unsigned S   = rowS(i);
    unsigned rlo = S / M_;
    unsigned Sh  = (rlo + 1u) * M_;
    unsigned jt  = Sh - S + i + 1u;
    Trow[i] = jt + ((i < B_ && jt > i + B_) ? 1u : 0u);
  }
  if (blockIdx.x == 0) {
    // E (4112 f32) + counter (1 u32), contiguous
    for (int r = t; r < 4128; r += 256) zbase[r] = 0u;
  }
}

// ---------------------------------------------------------------------------
// Kernel B: 128x256-tile upper-tri Gram, bf16 MFMA, 8 waves (2x4).
// K=128 as 4 phases of BK=32, 2-buffer LDS via global_load_lds(16B),
// ONE barrier per phase: vmcnt(0) -> s_barrier -> STAGE(ph+1) -> compute.
// The prefetch has the whole compute phase as latency cover; the trailing
// barrier is unnecessary because the stage-issue sits after the barrier
// that proves all waves consumed the buffer being overwritten.
// Epilogue: DPP rsum16, single-reduce uniform windows, plain float2 stores.
// ---------------------------------------------------------------------------
__global__ __launch_bounds__(512, 4) void nt_gemm(
    const short* __restrict__ nb, const unsigned* __restrict__ Trow,
    float2* __restrict__ part, float* __restrict__ posl) {
  // XCD-chunked bijective swizzle: 1056 = 8 * 132
  const int tb = ((int)blockIdx.x & 7) * 132 + ((int)blockIdx.x >> 3);
  int bi2 = (int)(2.0f * (32.0f - sqrtf(fmaxf(0.f, 1024.0f - (float)tb))));
  if (bi2 > 63) bi2 = 63;
  while (bi2 > 0 && tb < tile0(bi2)) --bi2;
  while (tb >= tile0(bi2 + 1)) ++bi2;
  const int jlo = bi2 >> 1;
  const int bj2 = jlo + (tb - tile0(bi2));

  __shared__ short As[2][128 * 32];     // 2 x 8KB
  __shared__ short Bs[2][256 * 32];     // 2 x 16KB
  __shared__ float2 red2[4][128];       // 4KB          total 52KB -> 3 blk/CU

  const int t    = threadIdx.x;
  const int lane = t & 63, wave = t >> 6;
  const int li   = lane & 15, hi = lane >> 4;
  const int wr   = wave >> 2, wc = wave & 3;   // 2x4 wave grid
  const int i0   = bi2 * 128, j0 = bj2 * 256;

  const short* gA = nb + (size_t)i0 * D_;
  const short* gB = nb + (size_t)j0 * D_;

#define STAGE(ko, buf) do {                                                   \
    { int e_ = t; int r_ = e_ >> 2, sl_ = e_ & 3, sg_ = sl_ ^ ((r_ >> 1) & 3);\
      __builtin_amdgcn_global_load_lds(                                       \
          (const AS1 void*)(gA + (size_t)r_ * D_ + (ko) + sg_ * 8),           \
          (AS3 void*)(&As[buf][e_ * 8]), 16, 0, 0); }                         \
    _Pragma("unroll")                                                         \
    for (int it_ = 0; it_ < 2; ++it_) {                                       \
      int e_ = it_ * 512 + t;                                                 \
      int r_ = e_ >> 2, sl_ = e_ & 3, sg_ = sl_ ^ ((r_ >> 1) & 3);            \
      __builtin_amdgcn_global_load_lds(                                       \
          (const AS1 void*)(gB + (size_t)r_ * D_ + (ko) + sg_ * 8),           \
          (AS3 void*)(&Bs[buf][e_ * 8]), 16, 0, 0); }                         \
  } while (0)

  STAGE(0, 0);   // prologue: phase 0 into buffer 0

  f32x4 acc[4][4];
  #pragma unroll
  for (int m = 0; m < 4; ++m)
    #pragma unroll
    for (int n = 0; n < 4; ++n) acc[m][n] = (f32x4){0.f, 0.f, 0.f, 0.f};

  const int sw = hi ^ ((li >> 1) & 3);   // swizzled 16B slot for ds_read

  #pragma unroll
  for (int ph = 0; ph < 4; ++ph) {
    // loads for buf (ph&1) were issued a full phase ago -> near-zero wait
    asm volatile("s_waitcnt vmcnt(0)" ::: "memory");
    __builtin_amdgcn_s_barrier();
    __builtin_amdgcn_sched_barrier(0);

    if (ph < 3) STAGE((ph + 1) * 32, (ph + 1) & 1);   // prefetch next phase

    const int cb = ph & 1;
    bf16x8 af[4], bfr[4];
    #pragma unroll
    for (int m = 0; m < 4; ++m)
      af[m] = *(const bf16x8*)(&As[cb][(wr * 64 + m * 16 + li) * 32 + sw * 8]);
    #pragma unroll
    for (int n = 0; n < 4; ++n)
      bfr[n] = *(const bf16x8*)(&Bs[cb][(wc * 64 + n * 16 + li) * 32 + sw * 8]);
    #pragma unroll
    for (int m = 0; m < 4; ++m)
      #pragma unroll
      for (int n = 0; n < 4; ++n)
        acc[m][n] = __builtin_amdgcn_mfma_f32_16x16x32_bf16(
            af[m], bfr[n], acc[m][n], 0, 0, 0);
  }
#undef STAGE

  // ---- epilogue: bucket sums, DPP reduce, cross-wave combine ----
  const bool isdiag = (bj2 == jlo);
  const bool ispost = (bj2 == jlo + 16);
  const bool special = isdiag | ispost;
  const unsigned jw0 = (unsigned)(j0 + wc * 64);

  #pragma unroll
  for (int m = 0; m < 4; ++m) {
    const uint4 T4 = *(const uint4*)(Trow + i0 + wr * 64 + m * 16 + hi * 4);
    const unsigned Ts[4] = {T4.x, T4.y, T4.z, T4.w};
    #pragma unroll
    for (int rg = 0; rg < 4; ++rg) {
      const unsigned i = (unsigned)(i0 + wr * 64 + m * 16 + hi * 4 + rg);
      const unsigned T = Ts[rg];
      float r0, r1;
      if (special) {
        float s0 = 0.f, s1 = 0.f;
        #pragma unroll
        for (int n = 0; n < 4; ++n) {
          const unsigned j = jw0 + n * 16 + (unsigned)li;
          const bool ip = ispost && (j == i + B_);
          if (ip) posl[i] = 2.0f * acc[m][n][rg];
          if ((j > i) && !ip) {
            float e = __expf(2.0f * acc[m][n][rg]);
            if (j < T) s0 += e; else s1 += e;
          }
        }
        r0 = rsum16(s0); r1 = rsum16(s1);
      } else if ((T > jw0) && (T < jw0 + 64u)) {   // straddle (rare)
        float s0 = 0.f, s1 = 0.f;
        #pragma unroll
        for (int n = 0; n < 4; ++n) {
          const unsigned j = jw0 + n * 16 + (unsigned)li;
          float e = __expf(2.0f * acc[m][n][rg]);
          if (j < T) s0 += e; else s1 += e;
        }
        r0 = rsum16(s0); r1 = rsum16(s1);
      } else {                                      // uniform bucket: 1 reduce
        float s = 0.f;
        #pragma unroll
        for (int n = 0; n < 4; ++n) s += __expf(2.0f * acc[m][n][rg]);
        s = rsum16(s);
        const bool lo = (T > jw0);                  // T outside window
        r0 = lo ? s : 0.f;
        r1 = lo ? 0.f : s;
      }
      if (li == 0)
        red2[wc][wr * 64 + m * 16 + hi * 4 + rg] = make_float2(r0, r1);
    }
  }
  __syncthreads();

  if (t < 128) {
    float2 s = make_float2(0.f, 0.f);
    #pragma unroll
    for (int w = 0; w < 4; ++w) {
      float2 v = red2[w][t];
      s.x += v.x; s.y += v.y;
    }
    part[(size_t)tb * 128 + t] = s;
  }
}

// ---------------------------------------------------------------------------
// Kernel C: fused rowreduce + finalize (R6-proven). 64 blocks; per-block:
// reduce partials for its 128-row panel, bucket-add into global E;
// LAST block (fence+counter) computes the loss.
// ---------------------------------------------------------------------------
__global__ __launch_bounds__(256) void nt_rowfin(
    const float2* __restrict__ part, const float* __restrict__ posl,
    float* __restrict__ E, unsigned* __restrict__ counter,
    float* __restrict__ out) {
  __shared__ float2 xch[128];
  __shared__ int lastflag;
  __shared__ double red[256];
  const int bi2 = (int)blockIdx.x;             // 0..63 == row panel
  const int t = threadIdx.x;
  const int lrow = t & 127, sh = t >> 7;
  const int base = tile0(bi2);
  const int cnt  = 32 - (bi2 >> 1);

  float2 s = make_float2(0.f, 0.f);
  for (int c = sh; c < cnt; c += 2) {
    float2 v = part[(size_t)(base + c) * 128 + lrow];
    s.x += v.x; s.y += v.y;
  }
  if (sh == 1) xch[lrow] = s;
  __syncthreads();
  if (sh == 0) {
    float2 v = xch[lrow];
    s.x += v.x; s.y += v.y;
    const unsigned i   = (unsigned)(bi2 * 128 + lrow);
    const unsigned rlo = rowS(i) / M_;
    atomicAdd(&E[rlo],      s.x);
    atomicAdd(&E[rlo + 1u], s.y);
  }
  __threadfence();
  __syncthreads();
  if (t == 0) lastflag = (atomicAdd(counter, 1u) == 63u) ? 1 : 0;
  __syncthreads();
  if (!lastflag) return;

  // ---- last block: loss = (1/B) * sum_r ( log(exp(posl)+E[r]) - posl[r] )
  __threadfence();
  double acc = 0.0;
  for (int r = t; r < (int)B_; r += 256) {
    float ev = atomicAdd(&E[r], 0.0f);      // coherent read
    float pl = posl[r];
    acc += (double)(logf(__expf(pl) + ev) - pl);
  }
  red[t] = acc;
  __syncthreads();
  for (int m = 128; m > 0; m >>= 1) {
    if (t < m) red[t] += red[t + m];
    __syncthreads();
  }
  if (t == 0) out[0] = (float)(red[0] / (double)B_);
}

// ---------------------------------------------------------------------------
extern "C" void kernel_launch(void* const* d_in, const int* in_sizes, int n_in,
                              void* d_out, int out_size, void* d_ws, size_t ws_size,
                              hipStream_t stream) {
  const float* zis = (const float*)d_in[0];
  const float* zjs = (const float*)d_in[1];
  float* out = (float*)d_out;

  char* ws = (char*)d_ws;
  short*    nb      = (short*)ws;                          // 2 MB
  unsigned* Trow    = (unsigned*)(ws + 2097152);           // 32 KB
  float*    posl    = (float*)(ws + 2129920);              // 16 KB
  float2*   part    = (float2*)(ws + 2146304);             // 1.08 MB
  float*    E       = (float*)(ws + 3227648);              // 4112 f32
  unsigned* counter = (unsigned*)(ws + 3244096);           // 1 u32
  unsigned* zb      = (unsigned*)E;                        // E+counter contiguous

  nt_norm  <<<dim3(N_ / 8), 256, 0, stream>>>(zis, zjs, nb, Trow, zb);
  nt_gemm  <<<dim3(NT2_),   512, 0, stream>>>(nb, Trow, part, posl);
  nt_rowfin<<<dim3(64),     256, 0, stream>>>(part, posl, E, counter, out);
}